// Round 1
// baseline (2886.367 us; speedup 1.0000x reference)
//
#include <hip/hip_runtime.h>
#include <hip/hip_bf16.h>

#define EPSV 1e-5f

namespace {
constexpr int Bn = 32, Sn = 1024, Dn = 768, Gn = 8, Cn = 64, Pn = 384;
constexpr int EFn = 1536, GFSn = 192, Nrows = Bn * Sn;  // 32768
}

// ---------------------------------------------------------------------------
// Generic 128x128 SGEMM, BK=16, 256 threads, 8x8 micro-tile (2x2 of 4x4).
// MODE 0: C = A@B + bias (bias may be null)
// MODE 1: C = ((A@B + bias) - m2[c]) * (g2[c]*rsqrt(v2[c]+eps)) + b2[c],
//         c = row % 64   (BN2 epilogue for the nc GEMM)
// ---------------------------------------------------------------------------
template <int MODE>
__global__ __launch_bounds__(256) void sgemm128(
    const float* __restrict__ A, const float* __restrict__ Bm,
    const float* __restrict__ bias, float* __restrict__ C,
    int M, int N, int K,
    const float* __restrict__ g2, const float* __restrict__ b2,
    const float* __restrict__ m2, const float* __restrict__ v2) {
  __shared__ float As[16][128];
  __shared__ float Bs[16][128];
  const int tid = threadIdx.x;
  const int tx = tid & 15, ty = tid >> 4;
  const int gm = blockIdx.y * 128, gn = blockIdx.x * 128;
  float acc[8][8] = {};

  for (int k0 = 0; k0 < K; k0 += 16) {
#pragma unroll
    for (int i = 0; i < 2; ++i) {
      const int idx = tid + i * 256;
      // A tile 128x16 (transposed into LDS)
      const int row = idx >> 2, kq = idx & 3;
      const float4 av = *reinterpret_cast<const float4*>(
          &A[(size_t)(gm + row) * K + k0 + kq * 4]);
      As[kq * 4 + 0][row] = av.x;
      As[kq * 4 + 1][row] = av.y;
      As[kq * 4 + 2][row] = av.z;
      As[kq * 4 + 3][row] = av.w;
      // B tile 16x128
      const int kr = idx >> 5, cq = idx & 31;
      *reinterpret_cast<float4*>(&Bs[kr][cq * 4]) =
          *reinterpret_cast<const float4*>(
              &Bm[(size_t)(k0 + kr) * N + gn + cq * 4]);
    }
    __syncthreads();
#pragma unroll
    for (int k = 0; k < 16; ++k) {
      alignas(16) float a[8], b[8];
      *reinterpret_cast<float4*>(&a[0]) =
          *reinterpret_cast<const float4*>(&As[k][ty * 4]);
      *reinterpret_cast<float4*>(&a[4]) =
          *reinterpret_cast<const float4*>(&As[k][64 + ty * 4]);
      *reinterpret_cast<float4*>(&b[0]) =
          *reinterpret_cast<const float4*>(&Bs[k][tx * 4]);
      *reinterpret_cast<float4*>(&b[4]) =
          *reinterpret_cast<const float4*>(&Bs[k][64 + tx * 4]);
#pragma unroll
      for (int i = 0; i < 8; ++i)
#pragma unroll
        for (int j = 0; j < 8; ++j) acc[i][j] += a[i] * b[j];
    }
    __syncthreads();
  }

#pragma unroll
  for (int i = 0; i < 8; ++i) {
    const int row = gm + ty * 4 + (i & 3) + (i >> 2) * 64;
    float scale = 1.f, shift = 0.f;
    if (MODE == 1) {
      const int c = row & 63;
      scale = g2[c] * rsqrtf(v2[c] + EPSV);
      shift = b2[c] - m2[c] * scale;
    }
#pragma unroll
    for (int jh = 0; jh < 2; ++jh) {
      const int cb = gn + tx * 4 + jh * 64;
      alignas(16) float o[4];
#pragma unroll
      for (int j = 0; j < 4; ++j) {
        float v = acc[i][jh * 4 + j];
        if (bias) v += bias[cb + j];
        if (MODE == 1) v = v * scale + shift;
        o[j] = v;
      }
      *reinterpret_cast<float4*>(&C[(size_t)row * N + cb]) =
          *reinterpret_cast<const float4*>(o);
    }
  }
}

// ---------------------------------------------------------------------------
// ga = sigmoid(fea @ W_ga + b_ga) : one wave per row, K=1536, G=8 outputs
// ---------------------------------------------------------------------------
__global__ __launch_bounds__(256) void ga_kernel(
    const float* __restrict__ fea, const float* __restrict__ W_ga,
    const float* __restrict__ b_ga, float* __restrict__ ga) {
  const int w = threadIdx.x >> 6, lane = threadIdx.x & 63;
  const int n = blockIdx.x * 4 + w;
  const float* fr = fea + (size_t)n * EFn;
  float acc[8] = {};
  for (int k = lane; k < EFn; k += 64) {
    const float f = fr[k];
    const float4 w0 = *reinterpret_cast<const float4*>(&W_ga[(size_t)k * 8]);
    const float4 w1 =
        *reinterpret_cast<const float4*>(&W_ga[(size_t)k * 8 + 4]);
    acc[0] += f * w0.x; acc[1] += f * w0.y;
    acc[2] += f * w0.z; acc[3] += f * w0.w;
    acc[4] += f * w1.x; acc[5] += f * w1.y;
    acc[6] += f * w1.z; acc[7] += f * w1.w;
  }
#pragma unroll
  for (int g = 0; g < 8; ++g) {
    float v = acc[g];
#pragma unroll
    for (int off = 32; off; off >>= 1) v += __shfl_xor(v, off);
    acc[g] = v;
  }
  if (lane < 8) {
    float v = acc[0];  // static-index select (avoid scratch spill)
#pragma unroll
    for (int g = 1; g < 8; ++g) v = (lane == g) ? acc[g] : v;
    v += b_ga[lane];
    ga[(size_t)n * 8 + lane] = 1.0f / (1.0f + expf(-v));
  }
}

// ---------------------------------------------------------------------------
// BN1 + group softmax (over C=64) + * ga  : one wave per (n, g), lane = c
// ---------------------------------------------------------------------------
__global__ __launch_bounds__(256) void bn_softmax_kernel(
    float* __restrict__ act, const float* __restrict__ g1,
    const float* __restrict__ b1, const float* __restrict__ m1,
    const float* __restrict__ v1, const float* __restrict__ ga) {
  const int w = threadIdx.x >> 6, lane = threadIdx.x & 63;
  const int idx = blockIdx.x * 4 + w;  // n*8+g
  const int n = idx >> 3, g = idx & 7;
  const int col = g * 64 + lane;
  const size_t p = (size_t)n * 512 + col;
  float val = act[p];
  const float scale = g1[col] * rsqrtf(v1[col] + EPSV);
  val = (val - m1[col]) * scale + b1[col];
  float mx = val;
#pragma unroll
  for (int off = 32; off; off >>= 1) mx = fmaxf(mx, __shfl_xor(mx, off));
  const float e = expf(val - mx);
  float sum = e;
#pragma unroll
  for (int off = 32; off; off >>= 1) sum += __shfl_xor(sum, off);
  act[p] = e / sum * ga[(size_t)n * 8 + g];
}

// ---------------------------------------------------------------------------
// cent partials: cent[b,c,f] = sum_{s,g} act[b,s*8+g,c] * fea[b,s, g*192+f]
// block = (b, chunk of 64 s), 192 threads (thread = f), partials to global
// ---------------------------------------------------------------------------
__global__ __launch_bounds__(192) void cent_kernel(
    const float* __restrict__ act, const float* __restrict__ fea,
    float* __restrict__ part) {
  __shared__ float sAct[512];
  const int b = blockIdx.x >> 4;
  const int chunk = blockIdx.x & 15;
  const int f = threadIdx.x;
  float acc[64] = {};
  const int s0 = chunk * 64;
  for (int s = s0; s < s0 + 64; ++s) {
    const int row = b * Sn + s;
    __syncthreads();
    for (int j = threadIdx.x; j < 512; j += 192)
      sAct[j] = act[(size_t)row * 512 + j];
    __syncthreads();
    const float* frow = fea + (size_t)row * EFn;
#pragma unroll
    for (int g = 0; g < 8; ++g) {
      const float fv = frow[g * GFSn + f];
#pragma unroll
      for (int c4 = 0; c4 < 16; ++c4) {
        const float4 a4 =
            *reinterpret_cast<const float4*>(&sAct[g * 64 + c4 * 4]);
        acc[c4 * 4 + 0] += a4.x * fv;
        acc[c4 * 4 + 1] += a4.y * fv;
        acc[c4 * 4 + 2] += a4.z * fv;
        acc[c4 * 4 + 3] += a4.w * fv;
      }
    }
  }
  float* pbase = part + ((size_t)chunk * Bn + b) * (64 * GFSn);
#pragma unroll
  for (int c = 0; c < 64; ++c) pbase[(size_t)c * GFSn + f] = acc[c];
}

__global__ __launch_bounds__(256) void cent_reduce(
    const float* __restrict__ part, float* __restrict__ cent) {
  const int idx = blockIdx.x * 256 + threadIdx.x;  // < 32*64*192
  float s = 0.f;
#pragma unroll
  for (int ch = 0; ch < 16; ++ch) s += part[(size_t)ch * 393216 + idx];
  cent[idx] = s;
}

// ---------------------------------------------------------------------------
// attention: wave per (b,s); lane = c for scores/softmax; PV coalesced on p
// ---------------------------------------------------------------------------
__global__ __launch_bounds__(256) void attn_kernel(
    const float* __restrict__ q, const float* __restrict__ kv,
    float* __restrict__ aout) {
  __shared__ float sQ[4][384];
  __shared__ float sA[4][64];
  const int w = threadIdx.x >> 6, lane = threadIdx.x & 63;
  const int r = blockIdx.x * 4 + w;  // 0..32767
  const int b = r >> 10;
  const float* qr = q + (size_t)r * 384;
#pragma unroll
  for (int j = 0; j < 6; ++j) sQ[w][lane + j * 64] = qr[lane + j * 64];
  __syncthreads();
  // scores: lane = c
  const float* krow = kv + (size_t)(b * 64 + lane) * 768;
  float s = 0.f;
#pragma unroll 4
  for (int p = 0; p < 384; p += 4) {
    const float4 k4 = *reinterpret_cast<const float4*>(&krow[p]);
    const float4 q4 = *reinterpret_cast<const float4*>(&sQ[w][p]);
    s += k4.x * q4.x + k4.y * q4.y + k4.z * q4.z + k4.w * q4.w;
  }
  s *= 0.05103103630798287f;  // 1/sqrt(384)
  float mx = s;
#pragma unroll
  for (int off = 32; off; off >>= 1) mx = fmaxf(mx, __shfl_xor(mx, off));
  const float e = expf(s - mx);
  float sum = e;
#pragma unroll
  for (int off = 32; off; off >>= 1) sum += __shfl_xor(sum, off);
  sA[w][lane] = e / sum;
  __syncthreads();
  float outv[6] = {};
  const float* vbase = kv + (size_t)b * 64 * 768 + 384;
  for (int c = 0; c < 64; ++c) {
    const float a = sA[w][c];
    const float* vrow = vbase + (size_t)c * 768;
#pragma unroll
    for (int j = 0; j < 6; ++j) outv[j] += a * vrow[lane + j * 64];
  }
  float* orow = aout + (size_t)r * 384;
#pragma unroll
  for (int j = 0; j < 6; ++j) orow[lane + j * 64] = outv[j];
}

// ---------------------------------------------------------------------------
extern "C" void kernel_launch(void* const* d_in, const int* in_sizes, int n_in,
                              void* d_out, int out_size, void* d_ws,
                              size_t ws_size, hipStream_t stream) {
  (void)in_sizes; (void)n_in; (void)out_size; (void)ws_size;
  const float* x      = (const float*)d_in[0];
  const float* W_exp  = (const float*)d_in[1];
  const float* b_exp  = (const float*)d_in[2];
  const float* W_ga   = (const float*)d_in[3];
  const float* b_ga   = (const float*)d_in[4];
  const float* bn1_g  = (const float*)d_in[5];
  const float* bn1_b  = (const float*)d_in[6];
  const float* bn1_m  = (const float*)d_in[7];
  const float* bn1_v  = (const float*)d_in[8];
  const float* cw     = (const float*)d_in[9];
  const float* W_proj = (const float*)d_in[10];
  const float* b_proj = (const float*)d_in[11];
  const float* bn2_g  = (const float*)d_in[12];
  const float* bn2_b  = (const float*)d_in[13];
  const float* bn2_m  = (const float*)d_in[14];
  const float* bn2_v  = (const float*)d_in[15];
  const float* Wq     = (const float*)d_in[16];
  const float* bq     = (const float*)d_in[17];
  const float* Wkv    = (const float*)d_in[18];
  const float* bkv    = (const float*)d_in[19];
  const float* Wp2    = (const float*)d_in[20];
  const float* bp2    = (const float*)d_in[21];
  float* out = (float*)d_out;

  char* ws = (char*)d_ws;
  // fea [32768,1536] f32 lives at 0; after cent it is dead and the region is
  // reused for q [32768,384] and aout [32768,384].
  float* fea  = (float*)(ws + 0);
  float* q    = (float*)(ws + 0);
  float* aout = (float*)(ws + 50331648ull);
  float* ga   = (float*)(ws + 201326592ull);
  float* act  = (float*)(ws + 202375168ull);
  float* cent = (float*)(ws + 269484032ull);
  float* nc   = (float*)(ws + 271056896ull);
  float* kvb  = (float*)(ws + 277348352ull);
  float* part = (float*)(ws + 283639808ull);  // 16 * 393216 f32

  dim3 blk(256);
  // 1. fea = x @ W_exp + b_exp        (32768,1536,K=768)
  sgemm128<0><<<dim3(EFn / 128, Nrows / 128), blk, 0, stream>>>(
      x, W_exp, b_exp, fea, Nrows, EFn, Dn, nullptr, nullptr, nullptr, nullptr);
  // 2. ga = sigmoid(fea @ W_ga + b_ga)
  ga_kernel<<<dim3(Nrows / 4), blk, 0, stream>>>(fea, W_ga, b_ga, ga);
  // 3. act = fea @ cluster_weights    (32768,512,K=1536)
  sgemm128<0><<<dim3(512 / 128, Nrows / 128), blk, 0, stream>>>(
      fea, cw, nullptr, act, Nrows, 512, EFn, nullptr, nullptr, nullptr,
      nullptr);
  // 4. BN1 + group softmax + *ga (in place)
  bn_softmax_kernel<<<dim3(Nrows * 8 / 4), blk, 0, stream>>>(
      act, bn1_g, bn1_b, bn1_m, bn1_v, ga);
  // 5. cent einsum (partials + reduce)
  cent_kernel<<<dim3(Bn * 16), dim3(192), 0, stream>>>(act, fea, part);
  cent_reduce<<<dim3(393216 / 256), blk, 0, stream>>>(part, cent);
  // 6. nc = BN2(cent @ W_proj + b_proj)   (2048,768,K=192)
  sgemm128<1><<<dim3(768 / 128, 2048 / 128), blk, 0, stream>>>(
      cent, W_proj, b_proj, nc, 2048, 768, GFSn, bn2_g, bn2_b, bn2_m, bn2_v);
  // 7. kv = nc @ Wkv + bkv                 (2048,768,K=768)
  sgemm128<0><<<dim3(768 / 128, 2048 / 128), blk, 0, stream>>>(
      nc, Wkv, bkv, kvb, 2048, 768, Dn, nullptr, nullptr, nullptr, nullptr);
  // 8. q = x @ Wq + bq                     (32768,384,K=768)
  sgemm128<0><<<dim3(384 / 128, Nrows / 128), blk, 0, stream>>>(
      x, Wq, bq, q, Nrows, Pn, Dn, nullptr, nullptr, nullptr, nullptr);
  // 9. attention -> aout
  attn_kernel<<<dim3(Nrows / 4), blk, 0, stream>>>(q, kvb, aout);
  // 10. out = aout @ Wp2 + bp2             (32768,768,K=384)
  sgemm128<0><<<dim3(768 / 128, Nrows / 128), blk, 0, stream>>>(
      aout, Wp2, bp2, out, Nrows, Dn, Pn, nullptr, nullptr, nullptr, nullptr);
}

// Round 2
// 1196.086 us; speedup vs baseline: 2.4132x; 2.4132x over previous
//
#include <hip/hip_runtime.h>
#include <hip/hip_bf16.h>

#define EPSV 1e-5f

namespace {
constexpr int Bn = 32, Sn = 1024, Dn = 768, Gn = 8, Cn = 64, Pn = 384;
constexpr int EFn = 1536, GFSn = 192, Nrows = Bn * Sn;  // 32768
}

typedef __attribute__((ext_vector_type(8))) short short8;
typedef __attribute__((ext_vector_type(4))) float f32x4;

__device__ __forceinline__ ushort f2bf(float f) {
  uint u = __builtin_bit_cast(uint, f);
  uint r = (u + 0x7fffu + ((u >> 16) & 1u)) >> 16;
  return (ushort)r;
}
__device__ __forceinline__ float bf2f(ushort h) {
  return __builtin_bit_cast(float, (uint)h << 16);
}
__device__ __forceinline__ void load16(const ushort* g, ushort* l) {
  __builtin_amdgcn_global_load_lds(
      (const __attribute__((address_space(1))) void*)g,
      (__attribute__((address_space(3))) void*)l, 16, 0, 0);
}

// ---------------------------------------------------------------------------
// bf16 MFMA GEMM, m97 structure: 128x128 tile, BK=32, 4 waves (2x2), each
// wave owns a 64x64 sub-tile = 4x4 fragments of 16x16x32.
// A: bf16 row-major [M][K]; BT: bf16 row-major [N][K] (B transposed);
// C: f32 or bf16 [M][N]. M%128==0, N%128==0, K%32==0.
// ---------------------------------------------------------------------------
template <int OUT_BF16>
__global__ __launch_bounds__(256) void gemm_bf16(
    const ushort* __restrict__ A, const ushort* __restrict__ BT,
    const float* __restrict__ bias, void* __restrict__ Cout,
    int M, int N, int K) {
  __shared__ ushort As[128 * 32];
  __shared__ ushort Bs[128 * 32];
  const int tid = threadIdx.x;
  const int wave = tid >> 6, lane = tid & 63;
  const int gm = blockIdx.y * 128, gn = blockIdx.x * 128;
  const int wr = wave >> 1, wc = wave & 1;

  // staging: chunk c in [0,512): LDS row = c>>2 (0..127), seg = c&3 (8 bf16)
  const int c0 = tid, c1 = tid + 256;
  const ushort* gA0 = A + (size_t)(gm + (c0 >> 2)) * K + (c0 & 3) * 8;
  const ushort* gA1 = A + (size_t)(gm + (c1 >> 2)) * K + (c1 & 3) * 8;
  const ushort* gB0 = BT + (size_t)(gn + (c0 >> 2)) * K + (c0 & 3) * 8;
  const ushort* gB1 = BT + (size_t)(gn + (c1 >> 2)) * K + (c1 & 3) * 8;
  // wave-uniform LDS bases (HW writes base + lane*16B)
  ushort* lA0 = &As[(size_t)wave * 64 * 8];
  ushort* lA1 = &As[(size_t)(256 + wave * 64) * 8];
  ushort* lB0 = &Bs[(size_t)wave * 64 * 8];
  ushort* lB1 = &Bs[(size_t)(256 + wave * 64) * 8];

  f32x4 acc[4][4] = {};
  const int arow = wr * 64 + (lane & 15);
  const int brow = wc * 64 + (lane & 15);
  const int koff = (lane >> 4) * 8;

  for (int k0 = 0; k0 < K; k0 += 32) {
    load16(gA0 + k0, lA0);
    load16(gA1 + k0, lA1);
    load16(gB0 + k0, lB0);
    load16(gB1 + k0, lB1);
    __syncthreads();
    short8 a[4], b[4];
#pragma unroll
    for (int m = 0; m < 4; ++m)
      a[m] = *reinterpret_cast<const short8*>(&As[(arow + m * 16) * 32 + koff]);
#pragma unroll
    for (int n = 0; n < 4; ++n)
      b[n] = *reinterpret_cast<const short8*>(&Bs[(brow + n * 16) * 32 + koff]);
#pragma unroll
    for (int m = 0; m < 4; ++m)
#pragma unroll
      for (int n = 0; n < 4; ++n)
        acc[m][n] =
            __builtin_amdgcn_mfma_f32_16x16x32_bf16(a[m], b[n], acc[m][n], 0, 0, 0);
    __syncthreads();
  }

  // epilogue: C/D layout col=lane&15, row=(lane>>4)*4+j  [m89-verified]
  const int crow0 = gm + wr * 64 + (lane >> 4) * 4;
  const int ccol0 = gn + wc * 64 + (lane & 15);
#pragma unroll
  for (int m = 0; m < 4; ++m)
#pragma unroll
    for (int n = 0; n < 4; ++n) {
      const int col = ccol0 + n * 16;
      const float bv = bias ? bias[col] : 0.f;
#pragma unroll
      for (int j = 0; j < 4; ++j) {
        const int row = crow0 + m * 16 + j;
        const float v = acc[m][n][j] + bv;
        if (OUT_BF16)
          ((ushort*)Cout)[(size_t)row * N + col] = f2bf(v);
        else
          ((float*)Cout)[(size_t)row * N + col] = v;
      }
    }
}

// ---------------------------------------------------------------------------
// f32 -> bf16 convert (vectorized float4 -> ushort4)
// ---------------------------------------------------------------------------
__global__ __launch_bounds__(256) void cvt_kernel(const float* __restrict__ in,
                                                  ushort* __restrict__ out,
                                                  int n4) {
  const int i = blockIdx.x * 256 + threadIdx.x;
  if (i >= n4) return;
  const float4 v = reinterpret_cast<const float4*>(in)[i];
  ushort4 o;
  o.x = f2bf(v.x); o.y = f2bf(v.y); o.z = f2bf(v.z); o.w = f2bf(v.w);
  reinterpret_cast<ushort4*>(out)[i] = o;
}

// ---------------------------------------------------------------------------
// transpose + convert: in f32 [R][C] -> out bf16 [C][R]   (R,C % 32 == 0)
// ---------------------------------------------------------------------------
__global__ __launch_bounds__(256) void tconv_kernel(const float* __restrict__ in,
                                                    ushort* __restrict__ out,
                                                    int R, int C) {
  __shared__ float t[32][33];
  const int tx = threadIdx.x & 31, ty = threadIdx.x >> 5;  // ty 0..7
  const int bc = blockIdx.x * 32, br = blockIdx.y * 32;
#pragma unroll
  for (int i = 0; i < 32; i += 8)
    t[ty + i][tx] = in[(size_t)(br + ty + i) * C + bc + tx];
  __syncthreads();
#pragma unroll
  for (int i = 0; i < 32; i += 8)
    out[(size_t)(bc + ty + i) * R + br + tx] = f2bf(t[tx][ty + i]);
}

// ---------------------------------------------------------------------------
// Generic 128x128 SGEMM (f32) for the small GEMMs (nc, kv). MODE as before.
// ---------------------------------------------------------------------------
template <int MODE>
__global__ __launch_bounds__(256) void sgemm128(
    const float* __restrict__ A, const float* __restrict__ Bm,
    const float* __restrict__ bias, float* __restrict__ C,
    int M, int N, int K,
    const float* __restrict__ g2, const float* __restrict__ b2,
    const float* __restrict__ m2, const float* __restrict__ v2) {
  __shared__ float As[16][128];
  __shared__ float Bs[16][128];
  const int tid = threadIdx.x;
  const int tx = tid & 15, ty = tid >> 4;
  const int gm = blockIdx.y * 128, gn = blockIdx.x * 128;
  float acc[8][8] = {};

  for (int k0 = 0; k0 < K; k0 += 16) {
#pragma unroll
    for (int i = 0; i < 2; ++i) {
      const int idx = tid + i * 256;
      const int row = idx >> 2, kq = idx & 3;
      const float4 av = *reinterpret_cast<const float4*>(
          &A[(size_t)(gm + row) * K + k0 + kq * 4]);
      As[kq * 4 + 0][row] = av.x;
      As[kq * 4 + 1][row] = av.y;
      As[kq * 4 + 2][row] = av.z;
      As[kq * 4 + 3][row] = av.w;
      const int kr = idx >> 5, cq = idx & 31;
      *reinterpret_cast<float4*>(&Bs[kr][cq * 4]) =
          *reinterpret_cast<const float4*>(
              &Bm[(size_t)(k0 + kr) * N + gn + cq * 4]);
    }
    __syncthreads();
#pragma unroll
    for (int k = 0; k < 16; ++k) {
      alignas(16) float a[8], b[8];
      *reinterpret_cast<float4*>(&a[0]) =
          *reinterpret_cast<const float4*>(&As[k][ty * 4]);
      *reinterpret_cast<float4*>(&a[4]) =
          *reinterpret_cast<const float4*>(&As[k][64 + ty * 4]);
      *reinterpret_cast<float4*>(&b[0]) =
          *reinterpret_cast<const float4*>(&Bs[k][tx * 4]);
      *reinterpret_cast<float4*>(&b[4]) =
          *reinterpret_cast<const float4*>(&Bs[k][64 + tx * 4]);
#pragma unroll
      for (int i = 0; i < 8; ++i)
#pragma unroll
        for (int j = 0; j < 8; ++j) acc[i][j] += a[i] * b[j];
    }
    __syncthreads();
  }

#pragma unroll
  for (int i = 0; i < 8; ++i) {
    const int row = gm + ty * 4 + (i & 3) + (i >> 2) * 64;
    float scale = 1.f, shift = 0.f;
    if (MODE == 1) {
      const int c = row & 63;
      scale = g2[c] * rsqrtf(v2[c] + EPSV);
      shift = b2[c] - m2[c] * scale;
    }
#pragma unroll
    for (int jh = 0; jh < 2; ++jh) {
      const int cb = gn + tx * 4 + jh * 64;
      alignas(16) float o[4];
#pragma unroll
      for (int j = 0; j < 4; ++j) {
        float v = acc[i][jh * 4 + j];
        if (bias) v += bias[cb + j];
        if (MODE == 1) v = v * scale + shift;
        o[j] = v;
      }
      *reinterpret_cast<float4*>(&C[(size_t)row * N + cb]) =
          *reinterpret_cast<const float4*>(o);
    }
  }
}

// ---------------------------------------------------------------------------
// ga = sigmoid(fea @ W_ga + b_ga) : one wave per row, K=1536, G=8 outputs
// fea is bf16 now.
// ---------------------------------------------------------------------------
__global__ __launch_bounds__(256) void ga_kernel(
    const ushort* __restrict__ fea, const float* __restrict__ W_ga,
    const float* __restrict__ b_ga, float* __restrict__ ga) {
  const int w = threadIdx.x >> 6, lane = threadIdx.x & 63;
  const int n = blockIdx.x * 4 + w;
  const ushort* fr = fea + (size_t)n * EFn;
  float acc[8] = {};
  for (int k = lane; k < EFn; k += 64) {
    const float f = bf2f(fr[k]);
    const float4 w0 = *reinterpret_cast<const float4*>(&W_ga[(size_t)k * 8]);
    const float4 w1 =
        *reinterpret_cast<const float4*>(&W_ga[(size_t)k * 8 + 4]);
    acc[0] += f * w0.x; acc[1] += f * w0.y;
    acc[2] += f * w0.z; acc[3] += f * w0.w;
    acc[4] += f * w1.x; acc[5] += f * w1.y;
    acc[6] += f * w1.z; acc[7] += f * w1.w;
  }
#pragma unroll
  for (int g = 0; g < 8; ++g) {
    float v = acc[g];
#pragma unroll
    for (int off = 32; off; off >>= 1) v += __shfl_xor(v, off);
    acc[g] = v;
  }
  if (lane < 8) {
    float v = acc[0];
#pragma unroll
    for (int g = 1; g < 8; ++g) v = (lane == g) ? acc[g] : v;
    v += b_ga[lane];
    ga[(size_t)n * 8 + lane] = 1.0f / (1.0f + expf(-v));
  }
}

// ---------------------------------------------------------------------------
// BN1 + group softmax (over C=64) + * ga  : one wave per (n, g), lane = c
// ---------------------------------------------------------------------------
__global__ __launch_bounds__(256) void bn_softmax_kernel(
    float* __restrict__ act, const float* __restrict__ g1,
    const float* __restrict__ b1, const float* __restrict__ m1,
    const float* __restrict__ v1, const float* __restrict__ ga) {
  const int w = threadIdx.x >> 6, lane = threadIdx.x & 63;
  const int idx = blockIdx.x * 4 + w;  // n*8+g
  const int n = idx >> 3, g = idx & 7;
  const int col = g * 64 + lane;
  const size_t p = (size_t)n * 512 + col;
  float val = act[p];
  const float scale = g1[col] * rsqrtf(v1[col] + EPSV);
  val = (val - m1[col]) * scale + b1[col];
  float mx = val;
#pragma unroll
  for (int off = 32; off; off >>= 1) mx = fmaxf(mx, __shfl_xor(mx, off));
  const float e = expf(val - mx);
  float sum = e;
#pragma unroll
  for (int off = 32; off; off >>= 1) sum += __shfl_xor(sum, off);
  act[p] = e / sum * ga[(size_t)n * 8 + g];
}

// ---------------------------------------------------------------------------
// cent partials: cent[b,c,f] = sum_{s,g} act[b,s*8+g,c] * fea[b,s, g*192+f]
// fea is bf16.
// ---------------------------------------------------------------------------
__global__ __launch_bounds__(192) void cent_kernel(
    const float* __restrict__ act, const ushort* __restrict__ fea,
    float* __restrict__ part) {
  __shared__ float sAct[512];
  const int b = blockIdx.x >> 4;
  const int chunk = blockIdx.x & 15;
  const int f = threadIdx.x;
  float acc[64] = {};
  const int s0 = chunk * 64;
  for (int s = s0; s < s0 + 64; ++s) {
    const int row = b * Sn + s;
    __syncthreads();
    for (int j = threadIdx.x; j < 512; j += 192)
      sAct[j] = act[(size_t)row * 512 + j];
    __syncthreads();
    const ushort* frow = fea + (size_t)row * EFn;
#pragma unroll
    for (int g = 0; g < 8; ++g) {
      const float fv = bf2f(frow[g * GFSn + f]);
#pragma unroll
      for (int c4 = 0; c4 < 16; ++c4) {
        const float4 a4 =
            *reinterpret_cast<const float4*>(&sAct[g * 64 + c4 * 4]);
        acc[c4 * 4 + 0] += a4.x * fv;
        acc[c4 * 4 + 1] += a4.y * fv;
        acc[c4 * 4 + 2] += a4.z * fv;
        acc[c4 * 4 + 3] += a4.w * fv;
      }
    }
  }
  float* pbase = part + ((size_t)chunk * Bn + b) * (64 * GFSn);
#pragma unroll
  for (int c = 0; c < 64; ++c) pbase[(size_t)c * GFSn + f] = acc[c];
}

__global__ __launch_bounds__(256) void cent_reduce(
    const float* __restrict__ part, float* __restrict__ cent) {
  const int idx = blockIdx.x * 256 + threadIdx.x;  // < 32*64*192
  float s = 0.f;
#pragma unroll
  for (int ch = 0; ch < 16; ++ch) s += part[(size_t)ch * 393216 + idx];
  cent[idx] = s;
}

// ---------------------------------------------------------------------------
// attention: wave per (b,s); lane = c for scores/softmax; PV coalesced on p
// q f32, kv f32, aout bf16.
// ---------------------------------------------------------------------------
__global__ __launch_bounds__(256) void attn_kernel(
    const float* __restrict__ q, const float* __restrict__ kv,
    ushort* __restrict__ aout) {
  __shared__ float sQ[4][384];
  __shared__ float sA[4][64];
  const int w = threadIdx.x >> 6, lane = threadIdx.x & 63;
  const int r = blockIdx.x * 4 + w;  // 0..32767
  const int b = r >> 10;
  const float* qr = q + (size_t)r * 384;
#pragma unroll
  for (int j = 0; j < 6; ++j) sQ[w][lane + j * 64] = qr[lane + j * 64];
  __syncthreads();
  const float* krow = kv + (size_t)(b * 64 + lane) * 768;
  float s = 0.f;
#pragma unroll 4
  for (int p = 0; p < 384; p += 4) {
    const float4 k4 = *reinterpret_cast<const float4*>(&krow[p]);
    const float4 q4 = *reinterpret_cast<const float4*>(&sQ[w][p]);
    s += k4.x * q4.x + k4.y * q4.y + k4.z * q4.z + k4.w * q4.w;
  }
  s *= 0.05103103630798287f;  // 1/sqrt(384)
  float mx = s;
#pragma unroll
  for (int off = 32; off; off >>= 1) mx = fmaxf(mx, __shfl_xor(mx, off));
  const float e = expf(s - mx);
  float sum = e;
#pragma unroll
  for (int off = 32; off; off >>= 1) sum += __shfl_xor(sum, off);
  sA[w][lane] = e / sum;
  __syncthreads();
  float outv[6] = {};
  const float* vbase = kv + (size_t)b * 64 * 768 + 384;
  for (int c = 0; c < 64; ++c) {
    const float a = sA[w][c];
    const float* vrow = vbase + (size_t)c * 768;
#pragma unroll
    for (int j = 0; j < 6; ++j) outv[j] += a * vrow[lane + j * 64];
  }
  ushort* orow = aout + (size_t)r * 384;
#pragma unroll
  for (int j = 0; j < 6; ++j) orow[lane + j * 64] = f2bf(outv[j]);
}

// ---------------------------------------------------------------------------
extern "C" void kernel_launch(void* const* d_in, const int* in_sizes, int n_in,
                              void* d_out, int out_size, void* d_ws,
                              size_t ws_size, hipStream_t stream) {
  (void)in_sizes; (void)n_in; (void)out_size; (void)ws_size;
  const float* x      = (const float*)d_in[0];
  const float* W_exp  = (const float*)d_in[1];
  const float* b_exp  = (const float*)d_in[2];
  const float* W_ga   = (const float*)d_in[3];
  const float* b_ga   = (const float*)d_in[4];
  const float* bn1_g  = (const float*)d_in[5];
  const float* bn1_b  = (const float*)d_in[6];
  const float* bn1_m  = (const float*)d_in[7];
  const float* bn1_v  = (const float*)d_in[8];
  const float* cw     = (const float*)d_in[9];
  const float* W_proj = (const float*)d_in[10];
  const float* b_proj = (const float*)d_in[11];
  const float* bn2_g  = (const float*)d_in[12];
  const float* bn2_b  = (const float*)d_in[13];
  const float* bn2_m  = (const float*)d_in[14];
  const float* bn2_v  = (const float*)d_in[15];
  const float* Wq     = (const float*)d_in[16];
  const float* bq     = (const float*)d_in[17];
  const float* Wkv    = (const float*)d_in[18];
  const float* bkv    = (const float*)d_in[19];
  const float* Wp2    = (const float*)d_in[20];
  const float* bp2    = (const float*)d_in[21];
  float* out = (float*)d_out;

  char* ws = (char*)d_ws;
  // layout (bytes); ws_size >= 308,805,632 (validated in R1)
  ushort* fea  = (ushort*)(ws + 0);             // 32768x1536 bf16, 100.66MB [1..5]
  float*  act  = (float*)(ws + 100663296ull);   // 32768x512 f32, 67MB      [3..5]
  ushort* xb   = (ushort*)(ws + 167772160ull);  // 32768x768 bf16, 50MB     [0..8]
  float*  ga   = (float*)(ws + 218103808ull);   // 1MB                      [2..4]
  float*  cent = (float*)(ws + 219152384ull);   // 1.5MB                    [5..6]
  float*  nc   = (float*)(ws + 220725248ull);   // 6.3MB                    [6..7]
  float*  kvb  = (float*)(ws + 227016704ull);   // 6.3MB                    [7..9]
  float*  part = (float*)(ws + 233308160ull);   // 25MB                     [5]
  ushort* WT1  = (ushort*)(ws + 258473984ull);  // W_exp^T 1536x768 bf16
  ushort* WT2  = (ushort*)(ws + 260833280ull);  // cw^T    512x1536 bf16
  ushort* WT3  = (ushort*)(ws + 262406144ull);  // Wq^T    384x768 bf16
  ushort* WT4  = (ushort*)(ws + 262995968ull);  // Wp2^T   768x384 bf16
  ushort* aout = (ushort*)(ws + 263585792ull);  // 32768x384 bf16, 25MB [9..10]
  float*  q    = (float*)(ws + 100663296ull);   // reuse act region (dead) [8..9]

  dim3 blk(256);
  // 0. conversions
  cvt_kernel<<<dim3((Nrows * Dn / 4 + 255) / 256), blk, 0, stream>>>(
      x, xb, Nrows * Dn / 4);
  tconv_kernel<<<dim3(EFn / 32, Dn / 32), blk, 0, stream>>>(W_exp, WT1, Dn, EFn);
  tconv_kernel<<<dim3(512 / 32, EFn / 32), blk, 0, stream>>>(cw, WT2, EFn, 512);
  tconv_kernel<<<dim3(Pn / 32, Dn / 32), blk, 0, stream>>>(Wq, WT3, Dn, Pn);
  tconv_kernel<<<dim3(Dn / 32, Pn / 32), blk, 0, stream>>>(Wp2, WT4, Pn, Dn);
  // 1. fea = bf16(x @ W_exp + b_exp)        (32768,1536,K=768)
  gemm_bf16<1><<<dim3(EFn / 128, Nrows / 128), blk, 0, stream>>>(
      xb, WT1, b_exp, fea, Nrows, EFn, Dn);
  // 2. ga = sigmoid(fea @ W_ga + b_ga)
  ga_kernel<<<dim3(Nrows / 4), blk, 0, stream>>>(fea, W_ga, b_ga, ga);
  // 3. act = fea @ cluster_weights          (32768,512,K=1536)
  gemm_bf16<0><<<dim3(512 / 128, Nrows / 128), blk, 0, stream>>>(
      fea, WT2, nullptr, act, Nrows, 512, EFn);
  // 4. BN1 + group softmax + *ga (in place)
  bn_softmax_kernel<<<dim3(Nrows * 8 / 4), blk, 0, stream>>>(
      act, bn1_g, bn1_b, bn1_m, bn1_v, ga);
  // 5. cent einsum (partials + reduce)
  cent_kernel<<<dim3(Bn * 16), dim3(192), 0, stream>>>(act, fea, part);
  cent_reduce<<<dim3(393216 / 256), blk, 0, stream>>>(part, cent);
  // 6. nc = BN2(cent @ W_proj + b_proj)     (2048,768,K=192) f32
  sgemm128<1><<<dim3(768 / 128, 2048 / 128), blk, 0, stream>>>(
      cent, W_proj, b_proj, nc, 2048, 768, GFSn, bn2_g, bn2_b, bn2_m, bn2_v);
  // 7. kv = nc @ Wkv + bkv                  (2048,768,K=768) f32
  sgemm128<0><<<dim3(768 / 128, 2048 / 128), blk, 0, stream>>>(
      nc, Wkv, bkv, kvb, 2048, 768, Dn, nullptr, nullptr, nullptr, nullptr);
  // 8. q = x @ Wq + bq                      (32768,384,K=768)
  gemm_bf16<0><<<dim3(Pn / 128, Nrows / 128), blk, 0, stream>>>(
      xb, WT3, bq, q, Nrows, Pn, Dn);
  // 9. attention -> aout (bf16)
  attn_kernel<<<dim3(Nrows / 4), blk, 0, stream>>>(q, kvb, aout);
  // 10. out = aout @ Wp2 + bp2              (32768,768,K=384)
  gemm_bf16<0><<<dim3(Dn / 128, Nrows / 128), blk, 0, stream>>>(
      aout, WT4, bp2, out, Nrows, Dn, Pn);
}

// Round 3
// 810.084 us; speedup vs baseline: 3.5630x; 1.4765x over previous
//
#include <hip/hip_runtime.h>
#include <hip/hip_bf16.h>

#define EPSV 1e-5f

namespace {
constexpr int Bn = 32, Sn = 1024, Dn = 768, Gn = 8, Cn = 64, Pn = 384;
constexpr int EFn = 1536, GFSn = 192, Nrows = Bn * Sn;  // 32768
}

typedef __attribute__((ext_vector_type(8))) short short8;
typedef __attribute__((ext_vector_type(4))) float f32x4;
typedef __attribute__((ext_vector_type(16))) float f32x16;

__device__ __forceinline__ ushort f2bf(float f) {
  uint u = __builtin_bit_cast(uint, f);
  uint r = (u + 0x7fffu + ((u >> 16) & 1u)) >> 16;
  return (ushort)r;
}
__device__ __forceinline__ uint pack2bf(float lo, float hi) {
  return (uint)f2bf(lo) | ((uint)f2bf(hi) << 16);
}
__device__ __forceinline__ float bf2f(ushort h) {
  return __builtin_bit_cast(float, (uint)h << 16);
}
__device__ __forceinline__ void load16(const ushort* g, ushort* l) {
  __builtin_amdgcn_global_load_lds(
      (const __attribute__((address_space(1))) void*)g,
      (__attribute__((address_space(3))) void*)l, 16, 0, 0);
}

// ---------------------------------------------------------------------------
// bf16 MFMA GEMM, m97 structure: 128x128 tile, BK=32, 4 waves (2x2).
// ---------------------------------------------------------------------------
template <int OUT_BF16>
__global__ __launch_bounds__(256) void gemm_bf16(
    const ushort* __restrict__ A, const ushort* __restrict__ BT,
    const float* __restrict__ bias, void* __restrict__ Cout,
    int M, int N, int K) {
  __shared__ ushort As[128 * 32];
  __shared__ ushort Bs[128 * 32];
  const int tid = threadIdx.x;
  const int wave = tid >> 6, lane = tid & 63;
  const int gm = blockIdx.y * 128, gn = blockIdx.x * 128;
  const int wr = wave >> 1, wc = wave & 1;

  const int c0 = tid, c1 = tid + 256;
  const ushort* gA0 = A + (size_t)(gm + (c0 >> 2)) * K + (c0 & 3) * 8;
  const ushort* gA1 = A + (size_t)(gm + (c1 >> 2)) * K + (c1 & 3) * 8;
  const ushort* gB0 = BT + (size_t)(gn + (c0 >> 2)) * K + (c0 & 3) * 8;
  const ushort* gB1 = BT + (size_t)(gn + (c1 >> 2)) * K + (c1 & 3) * 8;
  ushort* lA0 = &As[(size_t)wave * 64 * 8];
  ushort* lA1 = &As[(size_t)(256 + wave * 64) * 8];
  ushort* lB0 = &Bs[(size_t)wave * 64 * 8];
  ushort* lB1 = &Bs[(size_t)(256 + wave * 64) * 8];

  f32x4 acc[4][4] = {};
  const int arow = wr * 64 + (lane & 15);
  const int brow = wc * 64 + (lane & 15);
  const int koff = (lane >> 4) * 8;

  for (int k0 = 0; k0 < K; k0 += 32) {
    load16(gA0 + k0, lA0);
    load16(gA1 + k0, lA1);
    load16(gB0 + k0, lB0);
    load16(gB1 + k0, lB1);
    __syncthreads();
    short8 a[4], b[4];
#pragma unroll
    for (int m = 0; m < 4; ++m)
      a[m] = *reinterpret_cast<const short8*>(&As[(arow + m * 16) * 32 + koff]);
#pragma unroll
    for (int n = 0; n < 4; ++n)
      b[n] = *reinterpret_cast<const short8*>(&Bs[(brow + n * 16) * 32 + koff]);
#pragma unroll
    for (int m = 0; m < 4; ++m)
#pragma unroll
      for (int n = 0; n < 4; ++n)
        acc[m][n] =
            __builtin_amdgcn_mfma_f32_16x16x32_bf16(a[m], b[n], acc[m][n], 0, 0, 0);
    __syncthreads();
  }

  const int crow0 = gm + wr * 64 + (lane >> 4) * 4;
  const int ccol0 = gn + wc * 64 + (lane & 15);
#pragma unroll
  for (int m = 0; m < 4; ++m)
#pragma unroll
    for (int n = 0; n < 4; ++n) {
      const int col = ccol0 + n * 16;
      const float bv = bias ? bias[col] : 0.f;
#pragma unroll
      for (int j = 0; j < 4; ++j) {
        const int row = crow0 + m * 16 + j;
        const float v = acc[m][n][j] + bv;
        if (OUT_BF16)
          ((ushort*)Cout)[(size_t)row * N + col] = f2bf(v);
        else
          ((float*)Cout)[(size_t)row * N + col] = v;
      }
    }
}

// ---------------------------------------------------------------------------
// f32 -> bf16 convert
// ---------------------------------------------------------------------------
__global__ __launch_bounds__(256) void cvt_kernel(const float* __restrict__ in,
                                                  ushort* __restrict__ out,
                                                  int n4) {
  const int i = blockIdx.x * 256 + threadIdx.x;
  if (i >= n4) return;
  const float4 v = reinterpret_cast<const float4*>(in)[i];
  ushort4 o;
  o.x = f2bf(v.x); o.y = f2bf(v.y); o.z = f2bf(v.z); o.w = f2bf(v.w);
  reinterpret_cast<ushort4*>(out)[i] = o;
}

// ---------------------------------------------------------------------------
// transpose + convert: in f32 [R][C] -> out bf16 [C][R]
// ---------------------------------------------------------------------------
__global__ __launch_bounds__(256) void tconv_kernel(const float* __restrict__ in,
                                                    ushort* __restrict__ out,
                                                    int R, int C) {
  __shared__ float t[32][33];
  const int tx = threadIdx.x & 31, ty = threadIdx.x >> 5;
  const int bc = blockIdx.x * 32, br = blockIdx.y * 32;
#pragma unroll
  for (int i = 0; i < 32; i += 8)
    t[ty + i][tx] = in[(size_t)(br + ty + i) * C + bc + tx];
  __syncthreads();
#pragma unroll
  for (int i = 0; i < 32; i += 8)
    out[(size_t)(bc + ty + i) * R + br + tx] = f2bf(t[tx][ty + i]);
}

// ---------------------------------------------------------------------------
// f32 SGEMM for the small GEMMs.
// MODE 0: C=A@B+bias (f32).  MODE 1: + BN2 epilogue (f32).
// MODE 2: kv split epilogue -> k_bf [2048][384] bf16, vT_bf [32][384][64] bf16
// ---------------------------------------------------------------------------
template <int MODE>
__global__ __launch_bounds__(256) void sgemm128(
    const float* __restrict__ A, const float* __restrict__ Bm,
    const float* __restrict__ bias, float* __restrict__ C,
    int M, int N, int K,
    const float* __restrict__ g2, const float* __restrict__ b2,
    const float* __restrict__ m2, const float* __restrict__ v2,
    ushort* __restrict__ kq, ushort* __restrict__ vt) {
  __shared__ float As[16][128];
  __shared__ float Bs[16][128];
  const int tid = threadIdx.x;
  const int tx = tid & 15, ty = tid >> 4;
  const int gm = blockIdx.y * 128, gn = blockIdx.x * 128;
  float acc[8][8] = {};

  for (int k0 = 0; k0 < K; k0 += 16) {
#pragma unroll
    for (int i = 0; i < 2; ++i) {
      const int idx = tid + i * 256;
      const int row = idx >> 2, kqq = idx & 3;
      const float4 av = *reinterpret_cast<const float4*>(
          &A[(size_t)(gm + row) * K + k0 + kqq * 4]);
      As[kqq * 4 + 0][row] = av.x;
      As[kqq * 4 + 1][row] = av.y;
      As[kqq * 4 + 2][row] = av.z;
      As[kqq * 4 + 3][row] = av.w;
      const int kr = idx >> 5, cq = idx & 31;
      *reinterpret_cast<float4*>(&Bs[kr][cq * 4]) =
          *reinterpret_cast<const float4*>(
              &Bm[(size_t)(k0 + kr) * N + gn + cq * 4]);
    }
    __syncthreads();
#pragma unroll
    for (int k = 0; k < 16; ++k) {
      alignas(16) float a[8], b[8];
      *reinterpret_cast<float4*>(&a[0]) =
          *reinterpret_cast<const float4*>(&As[k][ty * 4]);
      *reinterpret_cast<float4*>(&a[4]) =
          *reinterpret_cast<const float4*>(&As[k][64 + ty * 4]);
      *reinterpret_cast<float4*>(&b[0]) =
          *reinterpret_cast<const float4*>(&Bs[k][tx * 4]);
      *reinterpret_cast<float4*>(&b[4]) =
          *reinterpret_cast<const float4*>(&Bs[k][64 + tx * 4]);
#pragma unroll
      for (int i = 0; i < 8; ++i)
#pragma unroll
        for (int j = 0; j < 8; ++j) acc[i][j] += a[i] * b[j];
    }
    __syncthreads();
  }

#pragma unroll
  for (int i = 0; i < 8; ++i) {
    const int row = gm + ty * 4 + (i & 3) + (i >> 2) * 64;
    float scale = 1.f, shift = 0.f;
    if (MODE == 1) {
      const int c = row & 63;
      scale = g2[c] * rsqrtf(v2[c] + EPSV);
      shift = b2[c] - m2[c] * scale;
    }
#pragma unroll
    for (int jh = 0; jh < 2; ++jh) {
      const int cb = gn + tx * 4 + jh * 64;
      alignas(16) float o[4];
#pragma unroll
      for (int j = 0; j < 4; ++j) {
        float v = acc[i][jh * 4 + j];
        if (bias) v += bias[cb + j];
        if (MODE == 1) v = v * scale + shift;
        o[j] = v;
      }
      if (MODE == 2) {
        if (cb < 384) {
          ushort4 ov;
          ov.x = f2bf(o[0]); ov.y = f2bf(o[1]);
          ov.z = f2bf(o[2]); ov.w = f2bf(o[3]);
          *reinterpret_cast<ushort4*>(&kq[(size_t)row * 384 + cb]) = ov;
        } else {
          const int b = row >> 6, c = row & 63;
#pragma unroll
          for (int j = 0; j < 4; ++j)
            vt[(size_t)b * 24576 + (size_t)(cb - 384 + j) * 64 + c] =
                f2bf(o[j]);
        }
      } else {
        *reinterpret_cast<float4*>(&C[(size_t)row * N + cb]) =
            *reinterpret_cast<const float4*>(o);
      }
    }
  }
}

// ---------------------------------------------------------------------------
// ga = sigmoid(fea @ W_ga + b_ga)
// ---------------------------------------------------------------------------
__global__ __launch_bounds__(256) void ga_kernel(
    const ushort* __restrict__ fea, const float* __restrict__ W_ga,
    const float* __restrict__ b_ga, float* __restrict__ ga) {
  const int w = threadIdx.x >> 6, lane = threadIdx.x & 63;
  const int n = blockIdx.x * 4 + w;
  const ushort* fr = fea + (size_t)n * EFn;
  float acc[8] = {};
  for (int k = lane; k < EFn; k += 64) {
    const float f = bf2f(fr[k]);
    const float4 w0 = *reinterpret_cast<const float4*>(&W_ga[(size_t)k * 8]);
    const float4 w1 =
        *reinterpret_cast<const float4*>(&W_ga[(size_t)k * 8 + 4]);
    acc[0] += f * w0.x; acc[1] += f * w0.y;
    acc[2] += f * w0.z; acc[3] += f * w0.w;
    acc[4] += f * w1.x; acc[5] += f * w1.y;
    acc[6] += f * w1.z; acc[7] += f * w1.w;
  }
#pragma unroll
  for (int g = 0; g < 8; ++g) {
    float v = acc[g];
#pragma unroll
    for (int off = 32; off; off >>= 1) v += __shfl_xor(v, off);
    acc[g] = v;
  }
  if (lane < 8) {
    float v = acc[0];
#pragma unroll
    for (int g = 1; g < 8; ++g) v = (lane == g) ? acc[g] : v;
    v += b_ga[lane];
    ga[(size_t)n * 8 + lane] = 1.0f / (1.0f + expf(-v));
  }
}

// ---------------------------------------------------------------------------
// BN1 + group softmax + * ga
// ---------------------------------------------------------------------------
__global__ __launch_bounds__(256) void bn_softmax_kernel(
    float* __restrict__ act, const float* __restrict__ g1,
    const float* __restrict__ b1, const float* __restrict__ m1,
    const float* __restrict__ v1, const float* __restrict__ ga) {
  const int w = threadIdx.x >> 6, lane = threadIdx.x & 63;
  const int idx = blockIdx.x * 4 + w;
  const int n = idx >> 3, g = idx & 7;
  const int col = g * 64 + lane;
  const size_t p = (size_t)n * 512 + col;
  float val = act[p];
  const float scale = g1[col] * rsqrtf(v1[col] + EPSV);
  val = (val - m1[col]) * scale + b1[col];
  float mx = val;
#pragma unroll
  for (int off = 32; off; off >>= 1) mx = fmaxf(mx, __shfl_xor(mx, off));
  const float e = expf(val - mx);
  float sum = e;
#pragma unroll
  for (int off = 32; off; off >>= 1) sum += __shfl_xor(sum, off);
  act[p] = e / sum * ga[(size_t)n * 8 + g];
}

// ---------------------------------------------------------------------------
// cent partials
// ---------------------------------------------------------------------------
__global__ __launch_bounds__(192) void cent_kernel(
    const float* __restrict__ act, const ushort* __restrict__ fea,
    float* __restrict__ part) {
  __shared__ float sAct[512];
  const int b = blockIdx.x >> 4;
  const int chunk = blockIdx.x & 15;
  const int f = threadIdx.x;
  float acc[64] = {};
  const int s0 = chunk * 64;
  for (int s = s0; s < s0 + 64; ++s) {
    const int row = b * Sn + s;
    __syncthreads();
    for (int j = threadIdx.x; j < 512; j += 192)
      sAct[j] = act[(size_t)row * 512 + j];
    __syncthreads();
    const ushort* frow = fea + (size_t)row * EFn;
#pragma unroll
    for (int g = 0; g < 8; ++g) {
      const float fv = bf2f(frow[g * GFSn + f]);
#pragma unroll
      for (int c4 = 0; c4 < 16; ++c4) {
        const float4 a4 =
            *reinterpret_cast<const float4*>(&sAct[g * 64 + c4 * 4]);
        acc[c4 * 4 + 0] += a4.x * fv;
        acc[c4 * 4 + 1] += a4.y * fv;
        acc[c4 * 4 + 2] += a4.z * fv;
        acc[c4 * 4 + 3] += a4.w * fv;
      }
    }
  }
  float* pbase = part + ((size_t)chunk * Bn + b) * (64 * GFSn);
#pragma unroll
  for (int c = 0; c < 64; ++c) pbase[(size_t)c * GFSn + f] = acc[c];
}

__global__ __launch_bounds__(256) void cent_reduce(
    const float* __restrict__ part, float* __restrict__ cent) {
  const int idx = blockIdx.x * 256 + threadIdx.x;
  float s = 0.f;
#pragma unroll
  for (int ch = 0; ch < 16; ++ch) s += part[(size_t)ch * 393216 + idx];
  cent[idx] = s;
}

// ---------------------------------------------------------------------------
// MFMA attention: one wave per 32 q-rows. All-register, no LDS, no barriers.
// S^T = mfma(K, Q)  (32x32x16, K-dim = p, 24 ksteps, 2 c-tiles)
// softmax in-register (in-lane 32 + shfl_xor 32)
// out^T = mfma(VT, P^T) per 32-wide p-tile (12 tiles x 4 kc)
// Layouts: q bf16 [32768][384]; k bf16 [2048][384]; vT bf16 [32][384][64].
// C/D map (m74/m101): col=lane&31, row=(reg&3)+8*(reg>>2)+4*(lane>>5)
// ---------------------------------------------------------------------------
__global__ __launch_bounds__(256) void attn_mfma(
    const ushort* __restrict__ qb, const ushort* __restrict__ kb,
    const ushort* __restrict__ vtb, ushort* __restrict__ aout) {
  const int wave = threadIdx.x >> 6, lane = threadIdx.x & 63;
  const int wrow = blockIdx.x * 4 + wave;  // 0..1023
  const int row0 = wrow * 32;
  const int b = row0 >> 10;
  const int l31 = lane & 31, hi = lane >> 5;

  // ---- QK^T ----
  f32x16 accs0 = 0.f, accs1 = 0.f;
  const ushort* qp = qb + (size_t)(row0 + l31) * 384 + hi * 8;
  const ushort* kp = kb + (size_t)(b * 64 + l31) * 384 + hi * 8;
#pragma unroll 4
  for (int ks = 0; ks < 24; ++ks) {
    const short8 bq = *reinterpret_cast<const short8*>(qp + ks * 16);
    const short8 a0 = *reinterpret_cast<const short8*>(kp + ks * 16);
    const short8 a1 = *reinterpret_cast<const short8*>(kp + 32 * 384 + ks * 16);
    accs0 = __builtin_amdgcn_mfma_f32_32x32x16_bf16(a0, bq, accs0, 0, 0, 0);
    accs1 = __builtin_amdgcn_mfma_f32_32x32x16_bf16(a1, bq, accs1, 0, 0, 0);
  }

  // ---- softmax over c (rows of S^T) for q-row row0+l31 ----
  const float alpha = 0.05103103630798287f;  // 1/sqrt(384)
  float p[32];
#pragma unroll
  for (int i = 0; i < 16; ++i) { p[i] = accs0[i]; p[16 + i] = accs1[i]; }
  float mx = p[0];
#pragma unroll
  for (int i = 1; i < 32; ++i) mx = fmaxf(mx, p[i]);
  mx = fmaxf(mx, __shfl_xor(mx, 32));
  float sum = 0.f;
#pragma unroll
  for (int i = 0; i < 32; ++i) {
    p[i] = expf((p[i] - mx) * alpha);
    sum += p[i];
  }
  sum += __shfl_xor(sum, 32);
  const float inv = 1.0f / sum;

  // pack p*inv -> bf16 pairs; own c's: c = 32*ct + (reg&3)+8*(reg>>2)+4*hi
  uint pk0[8], pk1[8];
#pragma unroll
  for (int ct = 0; ct < 2; ++ct)
#pragma unroll
    for (int rg = 0; rg < 4; ++rg) {
      pk0[ct * 4 + rg] =
          pack2bf(p[ct * 16 + rg * 4 + 0] * inv, p[ct * 16 + rg * 4 + 1] * inv);
      pk1[ct * 4 + rg] =
          pack2bf(p[ct * 16 + rg * 4 + 2] * inv, p[ct * 16 + rg * 4 + 3] * inv);
    }
  uint ex0[8], ex1[8];
#pragma unroll
  for (int i = 0; i < 8; ++i) {
    ex0[i] = __shfl_xor(pk0[i], 32);
    ex1[i] = __shfl_xor(pk1[i], 32);
  }

  // ---- PV: out^T[p][qrow], 12 p-tiles of 32 ----
  const ushort* vp = vtb + ((size_t)b * 384 + l31) * 64 + hi * 8;
  ushort* orow = aout + (size_t)(row0 + l31) * 384;
  for (int mt = 0; mt < 12; ++mt) {
    f32x16 acco = 0.f;
#pragma unroll
    for (int kc = 0; kc < 4; ++kc) {
      const short8 av = *reinterpret_cast<const short8*>(
          vp + (size_t)mt * 32 * 64 + kc * 16);
      const int base = (kc >> 1) * 4 + (kc & 1) * 2;  // + hi
      const uint o0 = hi ? pk0[base + 1] : pk0[base];
      const uint o1 = hi ? pk1[base + 1] : pk1[base];
      const uint e0 = hi ? ex0[base + 1] : ex0[base];
      const uint e1 = hi ? ex1[base + 1] : ex1[base];
      uint4 uu;
      uu.x = hi ? e0 : o0;
      uu.y = hi ? e1 : o1;
      uu.z = hi ? o0 : e0;
      uu.w = hi ? o1 : e1;
      const short8 bp = __builtin_bit_cast(short8, uu);
      acco = __builtin_amdgcn_mfma_f32_32x32x16_bf16(av, bp, acco, 0, 0, 0);
    }
    // write: p = mt*32 + 8*rg + 4*hi + j, qrow = row0 + l31
#pragma unroll
    for (int rg = 0; rg < 4; ++rg) {
      ushort4 ov;
      ov.x = f2bf(acco[rg * 4 + 0]);
      ov.y = f2bf(acco[rg * 4 + 1]);
      ov.z = f2bf(acco[rg * 4 + 2]);
      ov.w = f2bf(acco[rg * 4 + 3]);
      *reinterpret_cast<ushort4*>(&orow[mt * 32 + rg * 8 + hi * 4]) = ov;
    }
  }
}

// ---------------------------------------------------------------------------
extern "C" void kernel_launch(void* const* d_in, const int* in_sizes, int n_in,
                              void* d_out, int out_size, void* d_ws,
                              size_t ws_size, hipStream_t stream) {
  (void)in_sizes; (void)n_in; (void)out_size; (void)ws_size;
  const float* x      = (const float*)d_in[0];
  const float* W_exp  = (const float*)d_in[1];
  const float* b_exp  = (const float*)d_in[2];
  const float* W_ga   = (const float*)d_in[3];
  const float* b_ga   = (const float*)d_in[4];
  const float* bn1_g  = (const float*)d_in[5];
  const float* bn1_b  = (const float*)d_in[6];
  const float* bn1_m  = (const float*)d_in[7];
  const float* bn1_v  = (const float*)d_in[8];
  const float* cw     = (const float*)d_in[9];
  const float* W_proj = (const float*)d_in[10];
  const float* b_proj = (const float*)d_in[11];
  const float* bn2_g  = (const float*)d_in[12];
  const float* bn2_b  = (const float*)d_in[13];
  const float* bn2_m  = (const float*)d_in[14];
  const float* bn2_v  = (const float*)d_in[15];
  const float* Wq     = (const float*)d_in[16];
  const float* bq     = (const float*)d_in[17];
  const float* Wkv    = (const float*)d_in[18];
  const float* bkv    = (const float*)d_in[19];
  const float* Wp2    = (const float*)d_in[20];
  const float* bp2    = (const float*)d_in[21];
  float* out = (float*)d_out;

  char* ws = (char*)d_ws;
  ushort* fea  = (ushort*)(ws + 0);             // 100.66MB [1..5]
  float*  act  = (float*)(ws + 100663296ull);   // 67MB     [3..5]
  ushort* q_bf = (ushort*)(ws + 100663296ull);  // 25MB, reuses act [8..9]
  ushort* xb   = (ushort*)(ws + 167772160ull);  // 50MB     [0..8]
  float*  ga   = (float*)(ws + 218103808ull);   // 1MB      [2..4]
  float*  cent = (float*)(ws + 219152384ull);   // 1.5MB    [5..6]
  float*  nc   = (float*)(ws + 220725248ull);   // 6.3MB    [6..7]
  ushort* k_bf = (ushort*)(ws + 227016704ull);  // 1.5MB    [7..9]
  ushort* vT_bf= (ushort*)(ws + 228589568ull);  // 1.5MB    [7..9]
  float*  part = (float*)(ws + 230162432ull);   // 25MB     [5]
  ushort* WT1  = (ushort*)(ws + 255328256ull);  // W_exp^T bf16
  ushort* WT2  = (ushort*)(ws + 257687552ull);  // cw^T
  ushort* WT3  = (ushort*)(ws + 259260416ull);  // Wq^T
  ushort* WT4  = (ushort*)(ws + 259850240ull);  // Wp2^T
  ushort* aout = (ushort*)(ws + 260440064ull);  // 25MB     [9..10]

  dim3 blk(256);
  // 0. conversions
  cvt_kernel<<<dim3((Nrows * Dn / 4 + 255) / 256), blk, 0, stream>>>(
      x, xb, Nrows * Dn / 4);
  tconv_kernel<<<dim3(EFn / 32, Dn / 32), blk, 0, stream>>>(W_exp, WT1, Dn, EFn);
  tconv_kernel<<<dim3(512 / 32, EFn / 32), blk, 0, stream>>>(cw, WT2, EFn, 512);
  tconv_kernel<<<dim3(Pn / 32, Dn / 32), blk, 0, stream>>>(Wq, WT3, Dn, Pn);
  tconv_kernel<<<dim3(Dn / 32, Pn / 32), blk, 0, stream>>>(Wp2, WT4, Pn, Dn);
  // 1. fea = bf16(x @ W_exp + b_exp)
  gemm_bf16<1><<<dim3(EFn / 128, Nrows / 128), blk, 0, stream>>>(
      xb, WT1, b_exp, fea, Nrows, EFn, Dn);
  // 2. ga
  ga_kernel<<<dim3(Nrows / 4), blk, 0, stream>>>(fea, W_ga, b_ga, ga);
  // 3. act = fea @ cluster_weights
  gemm_bf16<0><<<dim3(512 / 128, Nrows / 128), blk, 0, stream>>>(
      fea, WT2, nullptr, act, Nrows, 512, EFn);
  // 4. BN1 + group softmax + *ga
  bn_softmax_kernel<<<dim3(Nrows * 8 / 4), blk, 0, stream>>>(
      act, bn1_g, bn1_b, bn1_m, bn1_v, ga);
  // 5. cent
  cent_kernel<<<dim3(Bn * 16), dim3(192), 0, stream>>>(act, fea, part);
  cent_reduce<<<dim3(393216 / 256), blk, 0, stream>>>(part, cent);
  // 6. nc = BN2(cent @ W_proj + b_proj)
  sgemm128<1><<<dim3(768 / 128, 2048 / 128), blk, 0, stream>>>(
      cent, W_proj, b_proj, nc, 2048, 768, GFSn, bn2_g, bn2_b, bn2_m, bn2_v,
      nullptr, nullptr);
  // 7. kv GEMM -> k_bf, vT_bf (bf16 split epilogue)
  sgemm128<2><<<dim3(768 / 128, 2048 / 128), blk, 0, stream>>>(
      nc, Wkv, bkv, nullptr, 2048, 768, Dn, nullptr, nullptr, nullptr, nullptr,
      k_bf, vT_bf);
  // 8. q = bf16(x @ Wq + bq)
  gemm_bf16<1><<<dim3(Pn / 128, Nrows / 128), blk, 0, stream>>>(
      xb, WT3, bq, q_bf, Nrows, Pn, Dn);
  // 9. attention (MFMA, registers only)
  attn_mfma<<<dim3(Nrows / 128), blk, 0, stream>>>(q_bf, k_bf, vT_bf, aout);
  // 10. out = aout @ Wp2 + bp2
  gemm_bf16<0><<<dim3(Dn / 128, Nrows / 128), blk, 0, stream>>>(
      aout, WT4, bp2, out, Nrows, Dn, Pn);
}

// Round 4
// 663.139 us; speedup vs baseline: 4.3526x; 1.2216x over previous
//
#include <hip/hip_runtime.h>
#include <hip/hip_bf16.h>

#define EPSV 1e-5f

namespace {
constexpr int Bn = 32, Sn = 1024, Dn = 768, Gn = 8, Cn = 64, Pn = 384;
constexpr int EFn = 1536, GFSn = 192, Nrows = Bn * Sn;  // 32768
}

typedef __attribute__((ext_vector_type(8))) short short8;
typedef __attribute__((ext_vector_type(4))) float f32x4;
typedef __attribute__((ext_vector_type(16))) float f32x16;

__device__ __forceinline__ ushort f2bf(float f) {
  uint u = __builtin_bit_cast(uint, f);
  uint r = (u + 0x7fffu + ((u >> 16) & 1u)) >> 16;
  return (ushort)r;
}
__device__ __forceinline__ uint pack2bf(float lo, float hi) {
  return (uint)f2bf(lo) | ((uint)f2bf(hi) << 16);
}
__device__ __forceinline__ float bf2f(ushort h) {
  return __builtin_bit_cast(float, (uint)h << 16);
}
__device__ __forceinline__ void load16(const ushort* g, ushort* l) {
  __builtin_amdgcn_global_load_lds(
      (const __attribute__((address_space(1))) void*)g,
      (__attribute__((address_space(3))) void*)l, 16, 0, 0);
}

// ---------------------------------------------------------------------------
// bf16 MFMA GEMM, m97 structure: 128x128 tile, BK=32, 4 waves (2x2).
// A: bf16 [M][K]; BT: bf16 [N][K]; C f32 or bf16.
// ---------------------------------------------------------------------------
template <int OUT_BF16>
__global__ __launch_bounds__(256) void gemm_bf16(
    const ushort* __restrict__ A, const ushort* __restrict__ BT,
    const float* __restrict__ bias, void* __restrict__ Cout,
    int M, int N, int K) {
  __shared__ ushort As[128 * 32];
  __shared__ ushort Bs[128 * 32];
  const int tid = threadIdx.x;
  const int wave = tid >> 6, lane = tid & 63;
  const int gm = blockIdx.y * 128, gn = blockIdx.x * 128;
  const int wr = wave >> 1, wc = wave & 1;

  const int c0 = tid, c1 = tid + 256;
  const ushort* gA0 = A + (size_t)(gm + (c0 >> 2)) * K + (c0 & 3) * 8;
  const ushort* gA1 = A + (size_t)(gm + (c1 >> 2)) * K + (c1 & 3) * 8;
  const ushort* gB0 = BT + (size_t)(gn + (c0 >> 2)) * K + (c0 & 3) * 8;
  const ushort* gB1 = BT + (size_t)(gn + (c1 >> 2)) * K + (c1 & 3) * 8;
  ushort* lA0 = &As[(size_t)wave * 64 * 8];
  ushort* lA1 = &As[(size_t)(256 + wave * 64) * 8];
  ushort* lB0 = &Bs[(size_t)wave * 64 * 8];
  ushort* lB1 = &Bs[(size_t)(256 + wave * 64) * 8];

  f32x4 acc[4][4] = {};
  const int arow = wr * 64 + (lane & 15);
  const int brow = wc * 64 + (lane & 15);
  const int koff = (lane >> 4) * 8;

  for (int k0 = 0; k0 < K; k0 += 32) {
    load16(gA0 + k0, lA0);
    load16(gA1 + k0, lA1);
    load16(gB0 + k0, lB0);
    load16(gB1 + k0, lB1);
    __syncthreads();
    short8 a[4], b[4];
#pragma unroll
    for (int m = 0; m < 4; ++m)
      a[m] = *reinterpret_cast<const short8*>(&As[(arow + m * 16) * 32 + koff]);
#pragma unroll
    for (int n = 0; n < 4; ++n)
      b[n] = *reinterpret_cast<const short8*>(&Bs[(brow + n * 16) * 32 + koff]);
#pragma unroll
    for (int m = 0; m < 4; ++m)
#pragma unroll
      for (int n = 0; n < 4; ++n)
        acc[m][n] =
            __builtin_amdgcn_mfma_f32_16x16x32_bf16(a[m], b[n], acc[m][n], 0, 0, 0);
    __syncthreads();
  }

  const int crow0 = gm + wr * 64 + (lane >> 4) * 4;
  const int ccol0 = gn + wc * 64 + (lane & 15);
#pragma unroll
  for (int m = 0; m < 4; ++m)
#pragma unroll
    for (int n = 0; n < 4; ++n) {
      const int col = ccol0 + n * 16;
      const float bv = bias ? bias[col] : 0.f;
#pragma unroll
      for (int j = 0; j < 4; ++j) {
        const int row = crow0 + m * 16 + j;
        const float v = acc[m][n][j] + bv;
        if (OUT_BF16)
          ((ushort*)Cout)[(size_t)row * N + col] = f2bf(v);
        else
          ((float*)Cout)[(size_t)row * N + col] = v;
      }
    }
}

// ---------------------------------------------------------------------------
// gemm_sm: actT[512][32768] = softmax-epilogue( WT2[512][1536] @ fea^T )
// Fuses BN1 + group softmax (over 64 rows = one group, within wr-half of the
// 128-row tile) + ga gating. Output bf16 actT.
// ---------------------------------------------------------------------------
__global__ __launch_bounds__(256) void gemm_sm(
    const ushort* __restrict__ A, const ushort* __restrict__ BT,
    const float* __restrict__ g1, const float* __restrict__ b1,
    const float* __restrict__ m1, const float* __restrict__ v1,
    const float* __restrict__ ga, ushort* __restrict__ actT) {
  constexpr int K = EFn, N = Nrows;
  __shared__ ushort As[128 * 32];
  __shared__ ushort Bs[128 * 32];
  __shared__ float sScale[128], sShift[128];
  const int tid = threadIdx.x;
  const int wave = tid >> 6, lane = tid & 63;
  const int gm = blockIdx.y * 128, gn = blockIdx.x * 128;
  const int wr = wave >> 1, wc = wave & 1;

  if (tid < 128) {
    const int row = gm + tid;
    const float sc = g1[row] * rsqrtf(v1[row] + EPSV);
    sScale[tid] = sc;
    sShift[tid] = b1[row] - m1[row] * sc;
  }

  const int c0 = tid, c1 = tid + 256;
  const ushort* gA0 = A + (size_t)(gm + (c0 >> 2)) * K + (c0 & 3) * 8;
  const ushort* gA1 = A + (size_t)(gm + (c1 >> 2)) * K + (c1 & 3) * 8;
  const ushort* gB0 = BT + (size_t)(gn + (c0 >> 2)) * K + (c0 & 3) * 8;
  const ushort* gB1 = BT + (size_t)(gn + (c1 >> 2)) * K + (c1 & 3) * 8;
  ushort* lA0 = &As[(size_t)wave * 64 * 8];
  ushort* lA1 = &As[(size_t)(256 + wave * 64) * 8];
  ushort* lB0 = &Bs[(size_t)wave * 64 * 8];
  ushort* lB1 = &Bs[(size_t)(256 + wave * 64) * 8];

  f32x4 acc[4][4] = {};
  const int arow = wr * 64 + (lane & 15);
  const int brow = wc * 64 + (lane & 15);
  const int koff = (lane >> 4) * 8;

  for (int k0 = 0; k0 < K; k0 += 32) {
    load16(gA0 + k0, lA0);
    load16(gA1 + k0, lA1);
    load16(gB0 + k0, lB0);
    load16(gB1 + k0, lB1);
    __syncthreads();
    short8 a[4], b[4];
#pragma unroll
    for (int m = 0; m < 4; ++m)
      a[m] = *reinterpret_cast<const short8*>(&As[(arow + m * 16) * 32 + koff]);
#pragma unroll
    for (int n = 0; n < 4; ++n)
      b[n] = *reinterpret_cast<const short8*>(&Bs[(brow + n * 16) * 32 + koff]);
#pragma unroll
    for (int m = 0; m < 4; ++m)
#pragma unroll
      for (int n = 0; n < 4; ++n)
        acc[m][n] =
            __builtin_amdgcn_mfma_f32_16x16x32_bf16(a[m], b[n], acc[m][n], 0, 0, 0);
    __syncthreads();
  }

  // epilogue: BN1 affine -> softmax over the 64 rows of this wr-group
  // (16 in-lane values + shfl_xor over lane^16, lane^32) -> *ga -> bf16 store
  const int l15 = lane & 15, l4 = lane >> 4;
  const int g = (gm >> 6) + wr;
#pragma unroll
  for (int n = 0; n < 4; ++n) {
    const int col = gn + wc * 64 + n * 16 + l15;
    float mx = -1e30f;
#pragma unroll
    for (int m = 0; m < 4; ++m)
#pragma unroll
      for (int j = 0; j < 4; ++j) {
        const int rl = wr * 64 + m * 16 + l4 * 4 + j;
        acc[m][n][j] = acc[m][n][j] * sScale[rl] + sShift[rl];
        mx = fmaxf(mx, acc[m][n][j]);
      }
    mx = fmaxf(mx, __shfl_xor(mx, 16));
    mx = fmaxf(mx, __shfl_xor(mx, 32));
    float sum = 0.f;
#pragma unroll
    for (int m = 0; m < 4; ++m)
#pragma unroll
      for (int j = 0; j < 4; ++j) {
        acc[m][n][j] = expf(acc[m][n][j] - mx);
        sum += acc[m][n][j];
      }
    sum += __shfl_xor(sum, 16);
    sum += __shfl_xor(sum, 32);
    const float sc = ga[(size_t)col * 8 + g] / sum;
#pragma unroll
    for (int m = 0; m < 4; ++m)
#pragma unroll
      for (int j = 0; j < 4; ++j) {
        const int rowg = gm + wr * 64 + m * 16 + l4 * 4 + j;
        actT[(size_t)rowg * N + col] = f2bf(acc[m][n][j] * sc);
      }
  }
}

// ---------------------------------------------------------------------------
// f32 -> bf16 convert
// ---------------------------------------------------------------------------
__global__ __launch_bounds__(256) void cvt_kernel(const float* __restrict__ in,
                                                  ushort* __restrict__ out,
                                                  int n4) {
  const int i = blockIdx.x * 256 + threadIdx.x;
  if (i >= n4) return;
  const float4 v = reinterpret_cast<const float4*>(in)[i];
  ushort4 o;
  o.x = f2bf(v.x); o.y = f2bf(v.y); o.z = f2bf(v.z); o.w = f2bf(v.w);
  reinterpret_cast<ushort4*>(out)[i] = o;
}

// ---------------------------------------------------------------------------
// transpose + convert: in f32 [R][C] -> out bf16 [C][R]
// ---------------------------------------------------------------------------
__global__ __launch_bounds__(256) void tconv_kernel(const float* __restrict__ in,
                                                    ushort* __restrict__ out,
                                                    int R, int C) {
  __shared__ float t[32][33];
  const int tx = threadIdx.x & 31, ty = threadIdx.x >> 5;
  const int bc = blockIdx.x * 32, br = blockIdx.y * 32;
#pragma unroll
  for (int i = 0; i < 32; i += 8)
    t[ty + i][tx] = in[(size_t)(br + ty + i) * C + bc + tx];
  __syncthreads();
#pragma unroll
  for (int i = 0; i < 32; i += 8)
    out[(size_t)(bc + ty + i) * R + br + tx] = f2bf(t[tx][ty + i]);
}

// ---------------------------------------------------------------------------
// bf16 transpose: fea [32768][1536] -> feaT [1536][32768], 64x64 tiles
// ---------------------------------------------------------------------------
__global__ __launch_bounds__(256) void trans_kernel(
    const ushort* __restrict__ in, ushort* __restrict__ out) {
  __shared__ ushort t[64][68];
  const int tid = threadIdx.x;
  const int f0 = blockIdx.x * 64;  // col tile in `in` (24 tiles)
  const int n0 = blockIdx.y * 64;  // row tile in `in` (512 tiles)
  const int r = tid >> 2, cq = tid & 3;
  const ushort* src = in + (size_t)(n0 + r) * EFn + f0 + cq * 16;
  *reinterpret_cast<uint4*>(&t[r][cq * 16]) =
      *reinterpret_cast<const uint4*>(src);
  *reinterpret_cast<uint4*>(&t[r][cq * 16 + 8]) =
      *reinterpret_cast<const uint4*>(src + 8);
  __syncthreads();
  const int fl = tid >> 2, q = tid & 3;
  ushort vbuf[16];
#pragma unroll
  for (int j = 0; j < 16; ++j) vbuf[j] = t[q * 16 + j][fl];
  ushort* dst = out + (size_t)(f0 + fl) * Nrows + n0 + q * 16;
  *reinterpret_cast<uint4*>(dst) = *reinterpret_cast<uint4*>(&vbuf[0]);
  *reinterpret_cast<uint4*>(dst + 8) = *reinterpret_cast<uint4*>(&vbuf[8]);
}

// ---------------------------------------------------------------------------
// f32 SGEMM for the small GEMMs (nc, kv). MODE 1: BN2 epilogue.
// MODE 2: kv split -> k_bf [2048][384] bf16, vT_bf [32][384][64] bf16
// ---------------------------------------------------------------------------
template <int MODE>
__global__ __launch_bounds__(256) void sgemm128(
    const float* __restrict__ A, const float* __restrict__ Bm,
    const float* __restrict__ bias, float* __restrict__ C,
    int M, int N, int K,
    const float* __restrict__ g2, const float* __restrict__ b2,
    const float* __restrict__ m2, const float* __restrict__ v2,
    ushort* __restrict__ kq, ushort* __restrict__ vt) {
  __shared__ float As[16][128];
  __shared__ float Bs[16][128];
  const int tid = threadIdx.x;
  const int tx = tid & 15, ty = tid >> 4;
  const int gm = blockIdx.y * 128, gn = blockIdx.x * 128;
  float acc[8][8] = {};

  for (int k0 = 0; k0 < K; k0 += 16) {
#pragma unroll
    for (int i = 0; i < 2; ++i) {
      const int idx = tid + i * 256;
      const int row = idx >> 2, kqq = idx & 3;
      const float4 av = *reinterpret_cast<const float4*>(
          &A[(size_t)(gm + row) * K + k0 + kqq * 4]);
      As[kqq * 4 + 0][row] = av.x;
      As[kqq * 4 + 1][row] = av.y;
      As[kqq * 4 + 2][row] = av.z;
      As[kqq * 4 + 3][row] = av.w;
      const int kr = idx >> 5, cq = idx & 31;
      *reinterpret_cast<float4*>(&Bs[kr][cq * 4]) =
          *reinterpret_cast<const float4*>(
              &Bm[(size_t)(k0 + kr) * N + gn + cq * 4]);
    }
    __syncthreads();
#pragma unroll
    for (int k = 0; k < 16; ++k) {
      alignas(16) float a[8], b[8];
      *reinterpret_cast<float4*>(&a[0]) =
          *reinterpret_cast<const float4*>(&As[k][ty * 4]);
      *reinterpret_cast<float4*>(&a[4]) =
          *reinterpret_cast<const float4*>(&As[k][64 + ty * 4]);
      *reinterpret_cast<float4*>(&b[0]) =
          *reinterpret_cast<const float4*>(&Bs[k][tx * 4]);
      *reinterpret_cast<float4*>(&b[4]) =
          *reinterpret_cast<const float4*>(&Bs[k][64 + tx * 4]);
#pragma unroll
      for (int i = 0; i < 8; ++i)
#pragma unroll
        for (int j = 0; j < 8; ++j) acc[i][j] += a[i] * b[j];
    }
    __syncthreads();
  }

#pragma unroll
  for (int i = 0; i < 8; ++i) {
    const int row = gm + ty * 4 + (i & 3) + (i >> 2) * 64;
    float scale = 1.f, shift = 0.f;
    if (MODE == 1) {
      const int c = row & 63;
      scale = g2[c] * rsqrtf(v2[c] + EPSV);
      shift = b2[c] - m2[c] * scale;
    }
#pragma unroll
    for (int jh = 0; jh < 2; ++jh) {
      const int cb = gn + tx * 4 + jh * 64;
      alignas(16) float o[4];
#pragma unroll
      for (int j = 0; j < 4; ++j) {
        float v = acc[i][jh * 4 + j];
        if (bias) v += bias[cb + j];
        if (MODE == 1) v = v * scale + shift;
        o[j] = v;
      }
      if (MODE == 2) {
        if (cb < 384) {
          ushort4 ov;
          ov.x = f2bf(o[0]); ov.y = f2bf(o[1]);
          ov.z = f2bf(o[2]); ov.w = f2bf(o[3]);
          *reinterpret_cast<ushort4*>(&kq[(size_t)row * 384 + cb]) = ov;
        } else {
          const int b = row >> 6, c = row & 63;
#pragma unroll
          for (int j = 0; j < 4; ++j)
            vt[(size_t)b * 24576 + (size_t)(cb - 384 + j) * 64 + c] =
                f2bf(o[j]);
        }
      } else {
        *reinterpret_cast<float4*>(&C[(size_t)row * N + cb]) =
            *reinterpret_cast<const float4*>(o);
      }
    }
  }
}

// ---------------------------------------------------------------------------
// ga = sigmoid(fea @ W_ga + b_ga)
// ---------------------------------------------------------------------------
__global__ __launch_bounds__(256) void ga_kernel(
    const ushort* __restrict__ fea, const float* __restrict__ W_ga,
    const float* __restrict__ b_ga, float* __restrict__ ga) {
  const int w = threadIdx.x >> 6, lane = threadIdx.x & 63;
  const int n = blockIdx.x * 4 + w;
  const ushort* fr = fea + (size_t)n * EFn;
  float acc[8] = {};
  for (int k = lane; k < EFn; k += 64) {
    const float f = bf2f(fr[k]);
    const float4 w0 = *reinterpret_cast<const float4*>(&W_ga[(size_t)k * 8]);
    const float4 w1 =
        *reinterpret_cast<const float4*>(&W_ga[(size_t)k * 8 + 4]);
    acc[0] += f * w0.x; acc[1] += f * w0.y;
    acc[2] += f * w0.z; acc[3] += f * w0.w;
    acc[4] += f * w1.x; acc[5] += f * w1.y;
    acc[6] += f * w1.z; acc[7] += f * w1.w;
  }
#pragma unroll
  for (int g = 0; g < 8; ++g) {
    float v = acc[g];
#pragma unroll
    for (int off = 32; off; off >>= 1) v += __shfl_xor(v, off);
    acc[g] = v;
  }
  if (lane < 8) {
    float v = acc[0];
#pragma unroll
    for (int g = 1; g < 8; ++g) v = (lane == g) ? acc[g] : v;
    v += b_ga[lane];
    ga[(size_t)n * 8 + lane] = 1.0f / (1.0f + expf(-v));
  }
}

// ---------------------------------------------------------------------------
// cent_mfma: block per (b,g). part[b*8+g][c=64][f=192] = A(64xK) @ B^T(192xK),
// K=1024 (s), A=actT rows, B=feaT rows. Reg-staged LDS, XOR-swizzled both
// sides (T2), double-buffered, 1 barrier / K-step.
// ---------------------------------------------------------------------------
__global__ __launch_bounds__(256) void cent_mfma(
    const ushort* __restrict__ actT, const ushort* __restrict__ feaT,
    float* __restrict__ part) {
  __shared__ ushort As[2][64 * 64];
  __shared__ ushort Bs[2][192 * 64];
  const int tid = threadIdx.x;
  const int wave = tid >> 6, lane = tid & 63;
  const int b = blockIdx.x >> 3, g = blockIdx.x & 7;
  const size_t colbase = (size_t)b * 1024;
  const int srow = tid >> 2, scp = (tid & 3) * 2;
  const ushort* gA = actT + (size_t)(g * 64 + srow) * Nrows + colbase;
  const ushort* gB0 = feaT + (size_t)(g * 192 + srow) * Nrows + colbase;
  const ushort* gB1 = gB0 + (size_t)64 * Nrows;
  const ushort* gB2 = gB0 + (size_t)128 * Nrows;

  uint4 ra[2], rb0[2], rb1[2], rb2[2];
  f32x4 acc[4][3] = {};
  const int l15 = lane & 15, hi = lane >> 4;
  const int sw = srow & 7;

#define CM_ISSUE(k0)                                                    \
  {                                                                     \
    _Pragma("unroll") for (int i = 0; i < 2; ++i) {                     \
      const int off = (k0) + (scp + i) * 8;                             \
      ra[i] = *reinterpret_cast<const uint4*>(gA + off);                \
      rb0[i] = *reinterpret_cast<const uint4*>(gB0 + off);              \
      rb1[i] = *reinterpret_cast<const uint4*>(gB1 + off);              \
      rb2[i] = *reinterpret_cast<const uint4*>(gB2 + off);              \
    }                                                                   \
  }
#define CM_STASH(buf)                                                   \
  {                                                                     \
    _Pragma("unroll") for (int i = 0; i < 2; ++i) {                     \
      const int c = scp + i;                                            \
      *reinterpret_cast<uint4*>(&As[buf][srow * 64 + ((c ^ sw) * 8)]) = \
          ra[i];                                                        \
      *reinterpret_cast<uint4*>(&Bs[buf][srow * 64 + ((c ^ sw) * 8)]) = \
          rb0[i];                                                       \
      *reinterpret_cast<uint4*>(                                        \
          &Bs[buf][(64 + srow) * 64 + ((c ^ sw) * 8)]) = rb1[i];        \
      *reinterpret_cast<uint4*>(                                        \
          &Bs[buf][(128 + srow) * 64 + ((c ^ sw) * 8)]) = rb2[i];       \
    }                                                                   \
  }

  CM_ISSUE(0);
  CM_STASH(0);
  for (int kk = 0; kk < 16; ++kk) {
    const int buf = kk & 1;
    if (kk < 15) CM_ISSUE((kk + 1) * 64);
    __syncthreads();
#pragma unroll
    for (int ks = 0; ks < 2; ++ks) {
      const int ch = ks * 4 + hi;
      short8 a[4], bb[3];
#pragma unroll
      for (int m = 0; m < 4; ++m) {
        const int r = m * 16 + l15;
        a[m] = *reinterpret_cast<const short8*>(
            &As[buf][r * 64 + ((ch ^ (r & 7)) * 8)]);
      }
#pragma unroll
      for (int nn = 0; nn < 3; ++nn) {
        const int r = wave * 48 + nn * 16 + l15;
        bb[nn] = *reinterpret_cast<const short8*>(
            &Bs[buf][r * 64 + ((ch ^ (r & 7)) * 8)]);
      }
#pragma unroll
      for (int m = 0; m < 4; ++m)
#pragma unroll
        for (int nn = 0; nn < 3; ++nn)
          acc[m][nn] = __builtin_amdgcn_mfma_f32_16x16x32_bf16(
              a[m], bb[nn], acc[m][nn], 0, 0, 0);
    }
    if (kk < 15) CM_STASH(buf ^ 1);
  }
#undef CM_ISSUE
#undef CM_STASH

  float* pb = part + (size_t)blockIdx.x * 12288;
#pragma unroll
  for (int m = 0; m < 4; ++m)
#pragma unroll
    for (int nn = 0; nn < 3; ++nn) {
      const int col = wave * 48 + nn * 16 + l15;
#pragma unroll
      for (int j = 0; j < 4; ++j) {
        const int row = m * 16 + hi * 4 + j;
        pb[row * 192 + col] = acc[m][nn][j];
      }
    }
}

__global__ __launch_bounds__(256) void cent_reduce8(
    const float* __restrict__ part, float* __restrict__ cent) {
  const int idx = blockIdx.x * 256 + threadIdx.x;  // < 393216
  const int b = idx / 12288, r = idx % 12288;
  float s = 0.f;
#pragma unroll
  for (int g = 0; g < 8; ++g) s += part[(size_t)(b * 8 + g) * 12288 + r];
  cent[idx] = s;
}

// ---------------------------------------------------------------------------
// MFMA attention (verified R3): one wave per 32 q-rows, all-register.
// ---------------------------------------------------------------------------
__global__ __launch_bounds__(256) void attn_mfma(
    const ushort* __restrict__ qb, const ushort* __restrict__ kb,
    const ushort* __restrict__ vtb, ushort* __restrict__ aout) {
  const int wave = threadIdx.x >> 6, lane = threadIdx.x & 63;
  const int wrow = blockIdx.x * 4 + wave;
  const int row0 = wrow * 32;
  const int b = row0 >> 10;
  const int l31 = lane & 31, hi = lane >> 5;

  f32x16 accs0 = 0.f, accs1 = 0.f;
  const ushort* qp = qb + (size_t)(row0 + l31) * 384 + hi * 8;
  const ushort* kp = kb + (size_t)(b * 64 + l31) * 384 + hi * 8;
#pragma unroll 4
  for (int ks = 0; ks < 24; ++ks) {
    const short8 bq = *reinterpret_cast<const short8*>(qp + ks * 16);
    const short8 a0 = *reinterpret_cast<const short8*>(kp + ks * 16);
    const short8 a1 = *reinterpret_cast<const short8*>(kp + 32 * 384 + ks * 16);
    accs0 = __builtin_amdgcn_mfma_f32_32x32x16_bf16(a0, bq, accs0, 0, 0, 0);
    accs1 = __builtin_amdgcn_mfma_f32_32x32x16_bf16(a1, bq, accs1, 0, 0, 0);
  }

  const float alpha = 0.05103103630798287f;
  float p[32];
#pragma unroll
  for (int i = 0; i < 16; ++i) { p[i] = accs0[i]; p[16 + i] = accs1[i]; }
  float mx = p[0];
#pragma unroll
  for (int i = 1; i < 32; ++i) mx = fmaxf(mx, p[i]);
  mx = fmaxf(mx, __shfl_xor(mx, 32));
  float sum = 0.f;
#pragma unroll
  for (int i = 0; i < 32; ++i) {
    p[i] = expf((p[i] - mx) * alpha);
    sum += p[i];
  }
  sum += __shfl_xor(sum, 32);
  const float inv = 1.0f / sum;

  uint pk0[8], pk1[8];
#pragma unroll
  for (int ct = 0; ct < 2; ++ct)
#pragma unroll
    for (int rg = 0; rg < 4; ++rg) {
      pk0[ct * 4 + rg] =
          pack2bf(p[ct * 16 + rg * 4 + 0] * inv, p[ct * 16 + rg * 4 + 1] * inv);
      pk1[ct * 4 + rg] =
          pack2bf(p[ct * 16 + rg * 4 + 2] * inv, p[ct * 16 + rg * 4 + 3] * inv);
    }
  uint ex0[8], ex1[8];
#pragma unroll
  for (int i = 0; i < 8; ++i) {
    ex0[i] = __shfl_xor(pk0[i], 32);
    ex1[i] = __shfl_xor(pk1[i], 32);
  }

  const ushort* vp = vtb + ((size_t)b * 384 + l31) * 64 + hi * 8;
  ushort* orow = aout + (size_t)(row0 + l31) * 384;
  for (int mt = 0; mt < 12; ++mt) {
    f32x16 acco = 0.f;
#pragma unroll
    for (int kc = 0; kc < 4; ++kc) {
      const short8 av = *reinterpret_cast<const short8*>(
          vp + (size_t)mt * 32 * 64 + kc * 16);
      const int base = (kc >> 1) * 4 + (kc & 1) * 2;
      const uint o0 = hi ? pk0[base + 1] : pk0[base];
      const uint o1 = hi ? pk1[base + 1] : pk1[base];
      const uint e0 = hi ? ex0[base + 1] : ex0[base];
      const uint e1 = hi ? ex1[base + 1] : ex1[base];
      uint4 uu;
      uu.x = hi ? e0 : o0;
      uu.y = hi ? e1 : o1;
      uu.z = hi ? o0 : e0;
      uu.w = hi ? o1 : e1;
      const short8 bp = __builtin_bit_cast(short8, uu);
      acco = __builtin_amdgcn_mfma_f32_32x32x16_bf16(av, bp, acco, 0, 0, 0);
    }
#pragma unroll
    for (int rg = 0; rg < 4; ++rg) {
      ushort4 ov;
      ov.x = f2bf(acco[rg * 4 + 0]);
      ov.y = f2bf(acco[rg * 4 + 1]);
      ov.z = f2bf(acco[rg * 4 + 2]);
      ov.w = f2bf(acco[rg * 4 + 3]);
      *reinterpret_cast<ushort4*>(&orow[mt * 32 + rg * 8 + hi * 4]) = ov;
    }
  }
}

// ---------------------------------------------------------------------------
extern "C" void kernel_launch(void* const* d_in, const int* in_sizes, int n_in,
                              void* d_out, int out_size, void* d_ws,
                              size_t ws_size, hipStream_t stream) {
  (void)in_sizes; (void)n_in; (void)out_size; (void)ws_size;
  const float* x      = (const float*)d_in[0];
  const float* W_exp  = (const float*)d_in[1];
  const float* b_exp  = (const float*)d_in[2];
  const float* W_ga   = (const float*)d_in[3];
  const float* b_ga   = (const float*)d_in[4];
  const float* bn1_g  = (const float*)d_in[5];
  const float* bn1_b  = (const float*)d_in[6];
  const float* bn1_m  = (const float*)d_in[7];
  const float* bn1_v  = (const float*)d_in[8];
  const float* cw     = (const float*)d_in[9];
  const float* W_proj = (const float*)d_in[10];
  const float* b_proj = (const float*)d_in[11];
  const float* bn2_g  = (const float*)d_in[12];
  const float* bn2_b  = (const float*)d_in[13];
  const float* bn2_m  = (const float*)d_in[14];
  const float* bn2_v  = (const float*)d_in[15];
  const float* Wq     = (const float*)d_in[16];
  const float* bq     = (const float*)d_in[17];
  const float* Wkv    = (const float*)d_in[18];
  const float* bkv    = (const float*)d_in[19];
  const float* Wp2    = (const float*)d_in[20];
  const float* bp2    = (const float*)d_in[21];
  float* out = (float*)d_out;

  char* ws = (char*)d_ws;
  // region A @0: fea bf16 100.66MB [steps 3..7]; aout bf16 25.2MB [11..12]
  ushort* fea  = (ushort*)(ws + 0);
  ushort* aout = (ushort*)(ws + 0);
  // region B @100663296: xb 50.3MB [1..4]; actT bf16 33.6MB [7..8]
  ushort* xb   = (ushort*)(ws + 100663296ull);
  ushort* actT = (ushort*)(ws + 100663296ull);
  ushort* q_bf = (ushort*)(ws + 150994944ull);  // 25.2MB [4..11]
  float*  ga   = (float*)(ws + 176160768ull);   // 1MB    [5..7]
  float*  part = (float*)(ws + 177209344ull);   // 12.6MB [8]
  float*  cent = (float*)(ws + 189792256ull);   // 1.5MB  [8..9]
  float*  nc   = (float*)(ws + 191365120ull);   // 6.3MB  [9..10]
  ushort* k_bf = (ushort*)(ws + 197656576ull);  // 1.5MB  [10..11]
  ushort* vT_bf= (ushort*)(ws + 199229440ull);  // 1.5MB  [10..11]
  ushort* WT1  = (ushort*)(ws + 200802304ull);
  ushort* WT2  = (ushort*)(ws + 203161600ull);
  ushort* WT3  = (ushort*)(ws + 204734464ull);
  ushort* WT4  = (ushort*)(ws + 205324288ull);
  // feaT lives in d_out (exactly 100,663,296 bytes), dead before final GEMM
  ushort* feaT = (ushort*)d_out;

  dim3 blk(256);
  // 1. conversions
  cvt_kernel<<<dim3((Nrows * Dn / 4 + 255) / 256), blk, 0, stream>>>(
      x, xb, Nrows * Dn / 4);
  tconv_kernel<<<dim3(EFn / 32, Dn / 32), blk, 0, stream>>>(W_exp, WT1, Dn, EFn);
  tconv_kernel<<<dim3(512 / 32, EFn / 32), blk, 0, stream>>>(cw, WT2, EFn, 512);
  tconv_kernel<<<dim3(Pn / 32, Dn / 32), blk, 0, stream>>>(Wq, WT3, Dn, Pn);
  tconv_kernel<<<dim3(Dn / 32, Pn / 32), blk, 0, stream>>>(Wp2, WT4, Pn, Dn);
  // 3. fea = bf16(x @ W_exp + b_exp)
  gemm_bf16<1><<<dim3(EFn / 128, Nrows / 128), blk, 0, stream>>>(
      xb, WT1, b_exp, fea, Nrows, EFn, Dn);
  // 4. q = bf16(x @ Wq + bq)   (last consumer of xb)
  gemm_bf16<1><<<dim3(Pn / 128, Nrows / 128), blk, 0, stream>>>(
      xb, WT3, bq, q_bf, Nrows, Pn, Dn);
  // 5. ga
  ga_kernel<<<dim3(Nrows / 4), blk, 0, stream>>>(fea, W_ga, b_ga, ga);
  // 6. feaT = transpose(fea)  (into d_out scratch)
  trans_kernel<<<dim3(EFn / 64, Nrows / 64), blk, 0, stream>>>(fea, feaT);
  // 7. actT = softmax-gemm(cw^T @ fea^T)  (BN1 + group softmax + ga fused)
  gemm_sm<<<dim3(Nrows / 128, 512 / 128), blk, 0, stream>>>(
      WT2, fea, bn1_g, bn1_b, bn1_m, bn1_v, ga, actT);
  // 8. cent = sum_g actT_g @ feaT_g^T
  cent_mfma<<<dim3(Bn * Gn), blk, 0, stream>>>(actT, feaT, part);
  cent_reduce8<<<dim3(393216 / 256), blk, 0, stream>>>(part, cent);
  // 9. nc = BN2(cent @ W_proj + b_proj)
  sgemm128<1><<<dim3(768 / 128, 2048 / 128), blk, 0, stream>>>(
      cent, W_proj, b_proj, nc, 2048, 768, GFSn, bn2_g, bn2_b, bn2_m, bn2_v,
      nullptr, nullptr);
  // 10. kv GEMM -> k_bf, vT_bf
  sgemm128<2><<<dim3(768 / 128, 2048 / 128), blk, 0, stream>>>(
      nc, Wkv, bkv, nullptr, 2048, 768, Dn, nullptr, nullptr, nullptr, nullptr,
      k_bf, vT_bf);
  // 11. attention
  attn_mfma<<<dim3(Nrows / 128), blk, 0, stream>>>(q_bf, k_bf, vT_bf, aout);
  // 12. out = aout @ Wp2 + bp2  (overwrites feaT scratch)
  gemm_bf16<0><<<dim3(Dn / 128, Nrows / 128), blk, 0, stream>>>(
      aout, WT4, bp2, out, Nrows, Dn, Pn);
}